// Round 12
// baseline (864.711 us; speedup 1.0000x reference)
//
#include <hip/hip_runtime.h>

// Problem constants (fixed by reference)
#define B_ 8
#define N_ 8192
#define E_ 131072
#define D_ 128
#define M_ (B_ * N_)          // 65536 rows
#define RNODES 256            // target nodes per agg block
constexpr float INV_SQRT_N = 0.011048543456039806f;  // 1/sqrt(8192)
constexpr float LN_EPS_C = 1e-5f;

typedef __attribute__((ext_vector_type(8))) short bf16x8;   // 8 bf16 (4 VGPRs)
typedef __attribute__((ext_vector_type(4))) float f32x4;    // MFMA C/D
typedef __attribute__((ext_vector_type(4))) float f32x4v;   // clang vec (NT ld/st)

static __device__ __forceinline__ unsigned short f2bf(float f) {
  unsigned u = __float_as_uint(f);
  u += 0x7fffu + ((u >> 16) & 1u);
  return (unsigned short)(u >> 16);
}
static __device__ __forceinline__ float bflo(unsigned u) {
  return __uint_as_float(u << 16);
}
static __device__ __forceinline__ float bfhi(unsigned u) {
  return __uint_as_float(u & 0xffff0000u);
}
static __device__ __forceinline__ bf16x8 cvt8v(const f32x4v a, const f32x4v b) {
  bf16x8 r;
  r[0] = (short)f2bf(a.x); r[1] = (short)f2bf(a.y);
  r[2] = (short)f2bf(a.z); r[3] = (short)f2bf(a.w);
  r[4] = (short)f2bf(b.x); r[5] = (short)f2bf(b.y);
  r[6] = (short)f2bf(b.z); r[7] = (short)f2bf(b.w);
  return r;
}

// ---------------------------------------------------------------------------
// K1: MFMA GEMM, hb = bf16(X@W^T + b). R9's proven per-wave structure:
// 256 blocks x 256 threads, 256 nodes/block. Wave: feature half hf=w&1,
// node group ng=w>>1; W-frags in registers (loaded once, fp32->bf16),
// strip loop of 8 x [NT X-loads + 16 MFMA + 4 uint2 stores].
// C/D (verified R6/R7): col=lane&15 -> node, row=(lane>>4)*4+reg -> feature.
// ---------------------------------------------------------------------------
__global__ __launch_bounds__(256, 4) void gemm_kernel(
    const float* __restrict__ X, const float* __restrict__ W,
    const float* __restrict__ bias, unsigned short* __restrict__ hb) {
  const int wave = threadIdx.x >> 6;
  const int lane = threadIdx.x & 63;
  const int m16 = lane & 15;
  const int q = lane >> 4;
  const int hf = wave & 1;     // feature half: feats [hf*64, +64)
  const int ng = wave >> 1;    // node group: nodes [ng*128, +128)

  bf16x8 wf[4][4];  // [kt4][t]
#pragma unroll
  for (int kt4 = 0; kt4 < 4; ++kt4) {
#pragma unroll
    for (int tt = 0; tt < 4; ++tt) {
      const float* wr = W + (size_t)(hf * 64 + tt * 16 + m16) * D_ +
                        kt4 * 32 + q * 8;
      wf[kt4][tt] = cvt8v(*(const f32x4v*)wr, *(const f32x4v*)(wr + 4));
    }
  }

  const int nbase0 = blockIdx.x * 256 + ng * 128;
#pragma unroll 2
  for (int s = 0; s < 8; ++s) {
    const int nbase = nbase0 + s * 16;
    const float* xrow = X + (size_t)(nbase + m16) * D_;

    f32x4 acc[4];
#pragma unroll
    for (int tt = 0; tt < 4; ++tt) acc[tt] = (f32x4){0.f, 0.f, 0.f, 0.f};

#pragma unroll
    for (int kt4 = 0; kt4 < 4; ++kt4) {
      const f32x4v xa = __builtin_nontemporal_load(
          (const f32x4v*)(xrow + kt4 * 32 + q * 8));
      const f32x4v xb = __builtin_nontemporal_load(
          (const f32x4v*)(xrow + kt4 * 32 + q * 8 + 4));
      const bf16x8 xf = cvt8v(xa, xb);
#pragma unroll
      for (int tt = 0; tt < 4; ++tt) {
        acc[tt] = __builtin_amdgcn_mfma_f32_16x16x32_bf16(wf[kt4][tt], xf,
                                                          acc[tt], 0, 0, 0);
      }
    }

    const size_t orow = (size_t)(nbase + m16) * D_;
#pragma unroll
    for (int tt = 0; tt < 4; ++tt) {
      const int f0 = hf * 64 + tt * 16 + q * 4;
      const float4 b4 = *(const float4*)&bias[f0];
      uint2 uu;
      uu.x = (unsigned)f2bf(acc[tt][0] + b4.x) |
             ((unsigned)f2bf(acc[tt][1] + b4.y) << 16);
      uu.y = (unsigned)f2bf(acc[tt][2] + b4.z) |
             ((unsigned)f2bf(acc[tt][3] + b4.w) << 16);
      *(uint2*)(hb + orow + f0) = uu;
    }
  }
}

// ---------------------------------------------------------------------------
// K2: LDS-accumulator aggregation + residual + LN + ReLU + mask. NO index
// structure, NO global atomics (R9-R11 lesson: any standalone CSR/bucket
// build costs 65-130 us). Block (batch=bid&7, range=bid>>3) owns 256 target
// nodes with agg[256][128] fp32 in LDS (128 KB). Scans its batch's edge list
// (coalesced, software-pipelined), ballots in-range hits (~2/64), wave-gathers
// each hit's 256 B source row from hb (XCD-L2-resident via bid&7==batch
// swizzle) and ds_add_f32's into LDS. Then finalize from LDS in-block.
// ---------------------------------------------------------------------------
__global__ __launch_bounds__(1024, 1) void agg_finalize_kernel(
    const unsigned short* __restrict__ hb, const int* __restrict__ eidx,
    const float* __restrict__ mask, const float* __restrict__ gamma,
    const float* __restrict__ beta, float* __restrict__ out) {
  __shared__ float agg[RNODES * D_];  // 128 KB
  const int batch = blockIdx.x & 7;   // XCD-locality heuristic
  const int ri = blockIdx.x >> 3;     // 0..31
  const int rbase = ri * RNODES;
  const int t = threadIdx.x;
  const int wave = t >> 6;
  const int lane = t & 63;

  // zero accumulators (coalesced, conflict-free)
#pragma unroll
  for (int i = 0; i < RNODES * D_ / 1024; ++i) agg[i * 1024 + t] = 0.f;
  __syncthreads();

  const int* tg = eidx + batch * 2 * E_ + E_;  // targets
  const int* sr = eidx + batch * 2 * E_;       // sources
  const unsigned* hub = (const unsigned*)hb + (size_t)batch * N_ * 64;

  // edge scan: wave handles 64 edges/chunk; 128 chunks; next chunk prefetched
  int e = wave * 64 + lane;
  int tv = tg[e];
  int sv = sr[e];
  for (int it = 0; it < E_ / 1024; ++it) {
    int tv_n = 0, sv_n = 0;
    if (it + 1 < E_ / 1024) {
      const int en = (it + 1) * 1024 + wave * 64 + lane;
      tv_n = tg[en];
      sv_n = sr[en];
    }
    const unsigned d = (unsigned)(tv - rbase);
    unsigned long long mb = __ballot(d < (unsigned)RNODES);
    while (mb) {
      const int j = __builtin_ctzll(mb);
      mb &= mb - 1;
      const int src = __shfl(sv, j, 64);
      const int dn = __shfl((int)d, j, 64);
      const unsigned u = hub[src * 64 + lane];  // feats 2*lane, 2*lane+1
      atomicAdd(&agg[dn * D_ + 2 * lane], bflo(u));
      atomicAdd(&agg[dn * D_ + 2 * lane + 1], bfhi(u));
    }
    tv = tv_n;
    sv = sv_n;
  }
  __syncthreads();

  // finalize: thread -> node nl=t>>2 (0..255), part p=t&3 (feats p*32..+31)
  const int nl = t >> 2;
  const int p = t & 3;
  const int row = batch * N_ + rbase + nl;
  const unsigned* hrow = hub + (size_t)(rbase + nl) * 64 + p * 16;
  const float* ag = &agg[nl * D_ + p * 32];

  float x[32];
  float s0 = 0.f, ss = 0.f;
#pragma unroll
  for (int i = 0; i < 16; ++i) {
    const unsigned u = hrow[i];
    const float v0 = bflo(u) + ag[2 * i] * INV_SQRT_N;
    const float v1 = bfhi(u) + ag[2 * i + 1] * INV_SQRT_N;
    x[2 * i] = v0;
    x[2 * i + 1] = v1;
    s0 += v0 + v1;
    ss += v0 * v0 + v1 * v1;
  }
  // reduce across the 4 threads sharing this node (lane bits 0..1)
  s0 += __shfl_xor(s0, 1, 64);
  ss += __shfl_xor(ss, 1, 64);
  s0 += __shfl_xor(s0, 2, 64);
  ss += __shfl_xor(ss, 2, 64);
  const float mu = s0 * (1.f / 128.f);
  float var = ss * (1.f / 128.f) - mu * mu;
  var = var < 0.f ? 0.f : var;
  const float rstd = rsqrtf(var + LN_EPS_C);
  const float m = mask[row];

  float* orow = out + (size_t)row * D_ + p * 32;
#pragma unroll
  for (int i = 0; i < 8; ++i) {
    const f32x4v g4 = *((const f32x4v*)(gamma + p * 32) + i);
    const f32x4v b4 = *((const f32x4v*)(beta + p * 32) + i);
    f32x4v o;
    o.x = (x[4 * i + 0] - mu) * rstd * g4.x + b4.x;
    o.y = (x[4 * i + 1] - mu) * rstd * g4.y + b4.y;
    o.z = (x[4 * i + 2] - mu) * rstd * g4.z + b4.z;
    o.w = (x[4 * i + 3] - mu) * rstd * g4.w + b4.w;
    o.x = (o.x > 0.f ? o.x : 0.f) * m;
    o.y = (o.y > 0.f ? o.y : 0.f) * m;
    o.z = (o.z > 0.f ? o.z : 0.f) * m;
    o.w = (o.w > 0.f ? o.w : 0.f) * m;
    __builtin_nontemporal_store(o, (f32x4v*)orow + i);
  }
}

// ---------------------------------------------------------------------------
extern "C" void kernel_launch(void* const* d_in, const int* in_sizes, int n_in,
                              void* d_out, int out_size, void* d_ws,
                              size_t ws_size, hipStream_t stream) {
  const float* X = (const float*)d_in[0];     // [B,N,128]
  const int* eidx = (const int*)d_in[1];      // [B,2,E]
  const float* mask = (const float*)d_in[2];  // [B,N]
  const float* W = (const float*)d_in[3];     // [128,128]
  const float* bias = (const float*)d_in[4];  // [128]
  const float* gamma = (const float*)d_in[5];
  const float* beta = (const float*)d_in[6];
  float* out = (float*)d_out;

  // workspace: hb only (16 MB), fully written by K1 before K2 reads it
  unsigned short* hb = (unsigned short*)d_ws;

  gemm_kernel<<<256, 256, 0, stream>>>(X, W, bias, hb);
  agg_finalize_kernel<<<256, 1024, 0, stream>>>(hb, eidx, mask, gamma, beta,
                                                out);
}

// Round 13
// 182.064 us; speedup vs baseline: 4.7495x; 4.7495x over previous
//
#include <hip/hip_runtime.h>

// Problem constants (fixed by reference)
#define B_ 8
#define N_ 8192
#define E_ 131072
#define D_ 128
#define M_ (B_ * N_)          // 65536 rows
#define SLOTS 64              // bucket capacity/node; P[Poisson(16)>64]~1e-21
constexpr float INV_SQRT_N = 0.011048543456039806f;  // 1/sqrt(8192)
constexpr float LN_EPS_C = 1e-5f;

typedef __attribute__((ext_vector_type(8))) short bf16x8;   // 8 bf16 (4 VGPRs)
typedef __attribute__((ext_vector_type(4))) float f32x4;    // MFMA C/D
typedef __attribute__((ext_vector_type(4))) float f32x4v;   // clang vec (NT ld/st)
typedef __attribute__((ext_vector_type(4))) unsigned u32x4; // 16 B gather load

static __device__ __forceinline__ unsigned short f2bf(float f) {
  unsigned u = __float_as_uint(f);
  u += 0x7fffu + ((u >> 16) & 1u);
  return (unsigned short)(u >> 16);
}
static __device__ __forceinline__ float bflo(unsigned u) {
  return __uint_as_float(u << 16);
}
static __device__ __forceinline__ float bfhi(unsigned u) {
  return __uint_as_float(u & 0xffff0000u);
}
static __device__ __forceinline__ bf16x8 cvt8v(const f32x4v a, const f32x4v b) {
  bf16x8 r;
  r[0] = (short)f2bf(a.x); r[1] = (short)f2bf(a.y);
  r[2] = (short)f2bf(a.z); r[3] = (short)f2bf(a.w);
  r[4] = (short)f2bf(b.x); r[5] = (short)f2bf(b.y);
  r[6] = (short)f2bf(b.z); r[7] = (short)f2bf(b.w);
  return r;
}

// ---------------------------------------------------------------------------
// K1 fused: blocks 0..255 = MFMA GEMM (R9/R12 proven structure);
//           blocks 256..1279 = direct-bucket fill with 4-edge MLP.
//
// GEMM: 256 nodes/block; wave: hf=w&1 (feature half), ng=w>>1 (128 nodes);
// W-frags in registers once; strip loop 8 x [NT X-loads + 16 MFMA + 4 uint2].
// C/D (verified R6/R7): col=lane&15 -> node, row=(lane>>4)*4+reg -> feature.
//
// Fill: thread owns 4 consecutive edges (int4 eidx reads); 4 INDEPENDENT
// returning atomics + 4 bucket stores overlap their memory-side round trips
// (R9 structure was 1 edge/thread = 1 round trip exposed per thread).
// ---------------------------------------------------------------------------
__global__ __launch_bounds__(256, 4) void gemm_fill_kernel(
    const float* __restrict__ X, const float* __restrict__ W,
    const float* __restrict__ bias, const int* __restrict__ eidx,
    int* __restrict__ cnt, unsigned short* __restrict__ bucket,
    unsigned short* __restrict__ hb) {
  if (blockIdx.x < 256) {
    const int wave = threadIdx.x >> 6;
    const int lane = threadIdx.x & 63;
    const int m16 = lane & 15;
    const int q = lane >> 4;
    const int hf = wave & 1;     // feature half: feats [hf*64, +64)
    const int ng = wave >> 1;    // node group: nodes [ng*128, +128)

    bf16x8 wf[4][4];  // [kt4][t]
#pragma unroll
    for (int kt4 = 0; kt4 < 4; ++kt4) {
#pragma unroll
      for (int tt = 0; tt < 4; ++tt) {
        const float* wr = W + (size_t)(hf * 64 + tt * 16 + m16) * D_ +
                          kt4 * 32 + q * 8;
        wf[kt4][tt] = cvt8v(*(const f32x4v*)wr, *(const f32x4v*)(wr + 4));
      }
    }

    const int nbase0 = blockIdx.x * 256 + ng * 128;
#pragma unroll 2
    for (int s = 0; s < 8; ++s) {
      const int nbase = nbase0 + s * 16;
      const float* xrow = X + (size_t)(nbase + m16) * D_;

      f32x4 acc[4];
#pragma unroll
      for (int tt = 0; tt < 4; ++tt) acc[tt] = (f32x4){0.f, 0.f, 0.f, 0.f};

#pragma unroll
      for (int kt4 = 0; kt4 < 4; ++kt4) {
        const f32x4v xa = __builtin_nontemporal_load(
            (const f32x4v*)(xrow + kt4 * 32 + q * 8));
        const f32x4v xb = __builtin_nontemporal_load(
            (const f32x4v*)(xrow + kt4 * 32 + q * 8 + 4));
        const bf16x8 xf = cvt8v(xa, xb);
#pragma unroll
        for (int tt = 0; tt < 4; ++tt) {
          acc[tt] = __builtin_amdgcn_mfma_f32_16x16x32_bf16(wf[kt4][tt], xf,
                                                            acc[tt], 0, 0, 0);
        }
      }

      const size_t orow = (size_t)(nbase + m16) * D_;
#pragma unroll
      for (int tt = 0; tt < 4; ++tt) {
        const int f0 = hf * 64 + tt * 16 + q * 4;
        const float4 b4 = *(const float4*)&bias[f0];
        uint2 uu;
        uu.x = (unsigned)f2bf(acc[tt][0] + b4.x) |
               ((unsigned)f2bf(acc[tt][1] + b4.y) << 16);
        uu.y = (unsigned)f2bf(acc[tt][2] + b4.z) |
               ((unsigned)f2bf(acc[tt][3] + b4.w) << 16);
        *(uint2*)(hb + orow + f0) = uu;
      }
    }
  } else {
    // direct bucket fill, 4 edges/thread, XCD-swizzled by batch
    const int f = blockIdx.x - 256;      // 0..1023
    const int batch = f & 7;
    const int chunk = f >> 3;            // 0..127
    const int base = batch * 2 * E_;
    const int e0 = chunk * 1024 + threadIdx.x * 4;
    const int4 sv = *(const int4*)&eidx[base + e0];        // 4 sources
    const int4 tv = *(const int4*)&eidx[base + E_ + e0];   // 4 targets
    const int nb = batch << 13;
    const int n0 = nb + tv.x, n1 = nb + tv.y, n2 = nb + tv.z, n3 = nb + tv.w;
    // 4 independent returning atomics -> round trips overlap
    const int p0 = atomicAdd(&cnt[n0], 1);
    const int p1 = atomicAdd(&cnt[n1], 1);
    const int p2 = atomicAdd(&cnt[n2], 1);
    const int p3 = atomicAdd(&cnt[n3], 1);
    if (p0 < SLOTS) bucket[(size_t)n0 * SLOTS + p0] = (unsigned short)sv.x;
    if (p1 < SLOTS) bucket[(size_t)n1 * SLOTS + p1] = (unsigned short)sv.y;
    if (p2 < SLOTS) bucket[(size_t)n2 * SLOTS + p2] = (unsigned short)sv.z;
    if (p3 < SLOTS) bucket[(size_t)n3 * SLOTS + p3] = (unsigned short)sv.w;
  }
}

// ---------------------------------------------------------------------------
// K2: gather + residual + LN + ReLU + mask (R11's verified 16-lane-row
// structure on the direct bucket). 4 rows/wave, 16 lanes/row, lane owns
// 8 feats (one u32x4 = dwordx4 per gathered row -> 1 KB per wave-instr).
// Row's 64 index slots = one 128 B line; lane c holds slots 4c..4c+3 (uint2).
// 8 independent gathers in flight per row group. XCD swizzle + NT out stores.
// ---------------------------------------------------------------------------
__global__ __launch_bounds__(256, 8) void gather_finalize_kernel(
    const unsigned short* __restrict__ hb, const unsigned short* __restrict__ bucket,
    const int* __restrict__ cnt, const float* __restrict__ mask,
    const float* __restrict__ gamma, const float* __restrict__ beta,
    float* __restrict__ out) {
  const int bid = blockIdx.x;
  const int batch = bid & 7;             // XCD-locality heuristic
  const int wave = threadIdx.x >> 6;
  const int lane = threadIdx.x & 63;
  const int g = lane >> 4;               // row within wave's 4
  const int c = lane & 15;               // 16 lanes per row
  const int r = (bid >> 3) * 16 + wave * 4 + g;  // 0..8191 within batch
  const int row = batch * N_ + r;

  const u32x4* hub4 = (const u32x4*)hb + (size_t)batch * N_ * 16;

  // independent early loads
  const int deg = min(cnt[row], SLOTS);
  const uint2 su = *(const uint2*)&bucket[(size_t)row * SLOTS + c * 4];
  const u32x4 ur = hub4[r * 16 + c];
  const float m = mask[row];

  float a[8];
#pragma unroll
  for (int k = 0; k < 8; ++k) a[k] = 0.f;

  int jb = 0;
  for (; jb + 8 <= deg; jb += 8) {
    const int L = jb >> 2;
    const unsigned w0 = (unsigned)__shfl((int)su.x, L, 16);      // jb, jb+1
    const unsigned w1 = (unsigned)__shfl((int)su.y, L, 16);      // jb+2, jb+3
    const unsigned w2 = (unsigned)__shfl((int)su.x, L + 1, 16);  // jb+4, jb+5
    const unsigned w3 = (unsigned)__shfl((int)su.y, L + 1, 16);  // jb+6, jb+7
    const int idx[8] = {(int)(w0 & 0xffff), (int)(w0 >> 16),
                        (int)(w1 & 0xffff), (int)(w1 >> 16),
                        (int)(w2 & 0xffff), (int)(w2 >> 16),
                        (int)(w3 & 0xffff), (int)(w3 >> 16)};
    u32x4 v[8];
#pragma unroll
    for (int i = 0; i < 8; ++i) v[i] = hub4[idx[i] * 16 + c];
#pragma unroll
    for (int i = 0; i < 8; ++i) {
      a[0] += bflo(v[i].x); a[1] += bfhi(v[i].x);
      a[2] += bflo(v[i].y); a[3] += bfhi(v[i].y);
      a[4] += bflo(v[i].z); a[5] += bfhi(v[i].z);
      a[6] += bflo(v[i].w); a[7] += bfhi(v[i].w);
    }
  }
  for (; jb < deg; ++jb) {
    const int L = jb >> 2;
    const unsigned w = ((jb >> 1) & 1) ? (unsigned)__shfl((int)su.y, L, 16)
                                       : (unsigned)__shfl((int)su.x, L, 16);
    const int idx = (jb & 1) ? (int)(w >> 16) : (int)(w & 0xffff);
    const u32x4 v = hub4[idx * 16 + c];
    a[0] += bflo(v.x); a[1] += bfhi(v.x);
    a[2] += bflo(v.y); a[3] += bfhi(v.y);
    a[4] += bflo(v.z); a[5] += bfhi(v.z);
    a[6] += bflo(v.w); a[7] += bfhi(v.w);
  }

  float x[8];
  x[0] = bflo(ur.x) + a[0] * INV_SQRT_N;
  x[1] = bfhi(ur.x) + a[1] * INV_SQRT_N;
  x[2] = bflo(ur.y) + a[2] * INV_SQRT_N;
  x[3] = bfhi(ur.y) + a[3] * INV_SQRT_N;
  x[4] = bflo(ur.z) + a[4] * INV_SQRT_N;
  x[5] = bfhi(ur.z) + a[5] * INV_SQRT_N;
  x[6] = bflo(ur.w) + a[6] * INV_SQRT_N;
  x[7] = bfhi(ur.w) + a[7] * INV_SQRT_N;

  float s0 = 0.f, ss = 0.f;
#pragma unroll
  for (int k = 0; k < 8; ++k) {
    s0 += x[k];
    ss += x[k] * x[k];
  }
#pragma unroll
  for (int o = 8; o >= 1; o >>= 1) {
    s0 += __shfl_xor(s0, o, 16);
    ss += __shfl_xor(ss, o, 16);
  }
  const float mu = s0 * (1.f / 128.f);
  float var = ss * (1.f / 128.f) - mu * mu;
  var = var < 0.f ? 0.f : var;
  const float rstd = rsqrtf(var + LN_EPS_C);

  const f32x4v g0 = *((const f32x4v*)gamma + c * 2);
  const f32x4v g1 = *((const f32x4v*)gamma + c * 2 + 1);
  const f32x4v b0 = *((const f32x4v*)beta + c * 2);
  const f32x4v b1 = *((const f32x4v*)beta + c * 2 + 1);

  f32x4v o0, o1;
  o0.x = (x[0] - mu) * rstd * g0.x + b0.x;
  o0.y = (x[1] - mu) * rstd * g0.y + b0.y;
  o0.z = (x[2] - mu) * rstd * g0.z + b0.z;
  o0.w = (x[3] - mu) * rstd * g0.w + b0.w;
  o1.x = (x[4] - mu) * rstd * g1.x + b1.x;
  o1.y = (x[5] - mu) * rstd * g1.y + b1.y;
  o1.z = (x[6] - mu) * rstd * g1.z + b1.z;
  o1.w = (x[7] - mu) * rstd * g1.w + b1.w;
  o0.x = (o0.x > 0.f ? o0.x : 0.f) * m;
  o0.y = (o0.y > 0.f ? o0.y : 0.f) * m;
  o0.z = (o0.z > 0.f ? o0.z : 0.f) * m;
  o0.w = (o0.w > 0.f ? o0.w : 0.f) * m;
  o1.x = (o1.x > 0.f ? o1.x : 0.f) * m;
  o1.y = (o1.y > 0.f ? o1.y : 0.f) * m;
  o1.z = (o1.z > 0.f ? o1.z : 0.f) * m;
  o1.w = (o1.w > 0.f ? o1.w : 0.f) * m;

  f32x4v* op = (f32x4v*)out + (size_t)row * 32 + c * 2;
  __builtin_nontemporal_store(o0, op);
  __builtin_nontemporal_store(o1, op + 1);
}

// ---------------------------------------------------------------------------
extern "C" void kernel_launch(void* const* d_in, const int* in_sizes, int n_in,
                              void* d_out, int out_size, void* d_ws,
                              size_t ws_size, hipStream_t stream) {
  const float* X = (const float*)d_in[0];     // [B,N,128]
  const int* eidx = (const int*)d_in[1];      // [B,2,E]
  const float* mask = (const float*)d_in[2];  // [B,N]
  const float* W = (const float*)d_in[3];     // [128,128]
  const float* bias = (const float*)d_in[4];  // [128]
  const float* gamma = (const float*)d_in[5];
  const float* beta = (const float*)d_in[6];
  float* out = (float*)d_out;

  // workspace (~24.3 MB)
  unsigned short* hb = (unsigned short*)d_ws;             // 16 MB bf16
  unsigned short* bucket = hb + (size_t)M_ * D_;          // 8 MB (M_*64 ushort)
  int* cnt = (int*)(bucket + (size_t)M_ * SLOTS);         // 256 KB

  (void)hipMemsetAsync(cnt, 0, (size_t)M_ * sizeof(int), stream);

  gemm_fill_kernel<<<256 + 1024, 256, 0, stream>>>(X, W, bias, eidx, cnt,
                                                   bucket, hb);
  gather_finalize_kernel<<<M_ / 16, 256, 0, stream>>>(hb, bucket, cnt, mask,
                                                      gamma, beta, out);
}